// Round 2
// baseline (256.748 us; speedup 1.0000x reference)
//
#include <hip/hip_runtime.h>
#include <hip/hip_bf16.h>

// GAT encoder, 2 layers. B=32, N=512, D=64, H=8, DK=8.
// Layer: xp = x@W -> s,t per head -> masked softmax over sources i per target j
//        -> out[j,h,:] = sum_i alpha * xp[i,h,:]  -> +bias, relu.
// Softmax shift m[j,h] = lrelu(max_i s[i,h] + t[j,h]) is a valid upper bound
// (leaky_relu monotone), so a single pass over i suffices (exp arg <= 0).

namespace {

constexpr int NB = 32;      // batch
constexpr int NN = 512;     // nodes
constexpr float SLOPE = 0.2f;

__device__ __forceinline__ float lrelu(float x) { return x > 0.f ? x : SLOPE * x; }

// ---------------- Kernel A: xp = x@W ; s = xp . a_src ; t = xp . a_dst -------
// grid: (B*N/32) blocks, 256 threads. Thread (r=tid>>3, h=tid&7) computes the
// 8 outputs of head h for row r.
__global__ __launch_bounds__(256) void gat_proj(
    const float* __restrict__ x,     // [B*N, 64]
    const float* __restrict__ W,     // [64, 64] row-major (k, c)
    const float* __restrict__ asrc,  // [8, 8]
    const float* __restrict__ adst,  // [8, 8]
    float* __restrict__ xp,          // [B*N, 64]
    float* __restrict__ s,           // [B*N, 8]
    float* __restrict__ t)           // [B*N, 8]
{
    __shared__ float Wl[64 * 64];
    __shared__ float xs[32 * 65];    // stride 65: kills 8-way bank conflict
    const int tid = threadIdx.x;
    const int row0 = blockIdx.x * 32;

    for (int q = tid; q < 4096; q += 256) Wl[q] = W[q];
    for (int q = tid; q < 2048; q += 256) xs[(q >> 6) * 65 + (q & 63)] = x[row0 * 64 + q];
    __syncthreads();

    const int r = tid >> 3, h = tid & 7;
    float acc[8] = {};
    const float* xr = &xs[r * 65];
    #pragma unroll 8
    for (int k = 0; k < 64; ++k) {
        const float xv = xr[k];
        #pragma unroll
        for (int d = 0; d < 8; ++d)
            acc[d] = fmaf(xv, Wl[k * 64 + h * 8 + d], acc[d]);
    }
    const int row = row0 + r;
    float4* xpo = reinterpret_cast<float4*>(&xp[row * 64 + h * 8]);
    xpo[0] = make_float4(acc[0], acc[1], acc[2], acc[3]);
    xpo[1] = make_float4(acc[4], acc[5], acc[6], acc[7]);

    float sv = 0.f, tv = 0.f;
    #pragma unroll
    for (int d = 0; d < 8; ++d) {
        sv = fmaf(acc[d], asrc[h * 8 + d], sv);
        tv = fmaf(acc[d], adst[h * 8 + d], tv);
    }
    s[row * 8 + h] = sv;
    t[row * 8 + h] = tv;
}

// ---------------- Kernel A2: smax[b,h] = max_i s[b,i,h] ---------------------
// grid: B blocks, 256 threads.
__global__ __launch_bounds__(256) void gat_smax(
    const float* __restrict__ s,     // [B*N, 8]
    float* __restrict__ smax)        // [B, 8]
{
    __shared__ float red[256];
    const int b = blockIdx.x, tid = threadIdx.x;
    const int h = tid & 7, i0 = tid >> 3;
    float m = -1e30f;
    for (int i = i0; i < NN; i += 32)
        m = fmaxf(m, s[(b * NN + i) * 8 + h]);
    red[tid] = m;
    __syncthreads();
    for (int off = 128; off >= 8; off >>= 1) {
        if (tid < off) red[tid] = fmaxf(red[tid], red[tid + off]);
        __syncthreads();
    }
    if (tid < 8) smax[b * 8 + tid] = red[tid];
}

// ---------------- Kernel B: masked softmax over i + aggregation -------------
// grid: (N/32, B); 256 threads; thread (jj=tid>>3, h=tid&7) owns target
// j = j0+jj, head h; accumulates acc[8] over all 512 sources i.
template <bool BF16OUT>
__global__ __launch_bounds__(256) void gat_aggr(
    const float* __restrict__ xp,    // [B*N, 64]
    const float* __restrict__ s,     // [B*N, 8]
    const float* __restrict__ t,     // [B*N, 8]
    const float* __restrict__ smax,  // [B, 8]
    const int*   __restrict__ adj,   // [B, N, N]  adj[b,i,j]
    const float* __restrict__ bias,  // [64]
    void* __restrict__ outp)         // [B*N, 64] f32 or bf16
{
    __shared__ float xpl[32 * 64];   // xp chunk: 32 sources x 64
    __shared__ float sl[32 * 8];     // s  chunk: 32 sources x 8 heads
    __shared__ float ml[32 * 32];    // mask chunk: 32 sources x 32 targets (0/1)

    const int tid = threadIdx.x;
    const int b = blockIdx.y;
    const int j0 = blockIdx.x * 32;
    const int jj = tid >> 3, h = tid & 7;
    const int j = j0 + jj;

    const float tv = t[(b * NN + j) * 8 + h];
    const float m = lrelu(smax[b * 8 + h] + tv);   // upper bound on all e

    float acc[8] = {};
    float l = 0.f;

    for (int i0 = 0; i0 < NN; i0 += 32) {
        __syncthreads();
        // stage xp chunk (512 float4)
        {
            const float4* src = reinterpret_cast<const float4*>(&xp[(b * NN + i0) * 64]);
            float4* dst = reinterpret_cast<float4*>(xpl);
            dst[tid] = src[tid];
            dst[tid + 256] = src[tid + 256];
        }
        // stage s chunk (256 floats)
        sl[tid] = s[(b * NN + i0) * 8 + tid];
        // stage mask chunk (32 i x 32 j), coalesced along j
        #pragma unroll
        for (int rep = 0; rep < 4; ++rep) {
            const int q = rep * 256 + tid;
            const int ii = q >> 5, jc = q & 31;
            const int gi = i0 + ii;
            const int av = adj[(b * NN + gi) * NN + j0 + jc];
            ml[q] = (av != 0 || gi == j0 + jc) ? 1.0f : 0.0f;
        }
        __syncthreads();

        #pragma unroll
        for (int ii = 0; ii < 32; ++ii) {
            const float e = lrelu(sl[ii * 8 + h] + tv);
            const float p = ml[ii * 32 + jj] * __expf(e - m);
            l += p;
            const float4* xr = reinterpret_cast<const float4*>(&xpl[ii * 64 + h * 8]);
            const float4 xa = xr[0], xb = xr[1];
            acc[0] = fmaf(p, xa.x, acc[0]);
            acc[1] = fmaf(p, xa.y, acc[1]);
            acc[2] = fmaf(p, xa.z, acc[2]);
            acc[3] = fmaf(p, xa.w, acc[3]);
            acc[4] = fmaf(p, xb.x, acc[4]);
            acc[5] = fmaf(p, xb.y, acc[5]);
            acc[6] = fmaf(p, xb.z, acc[6]);
            acc[7] = fmaf(p, xb.w, acc[7]);
        }
    }

    const float rec = 1.0f / l;
    float o[8];
    #pragma unroll
    for (int d = 0; d < 8; ++d)
        o[d] = fmaxf(fmaf(acc[d], rec, bias[h * 8 + d]), 0.0f);

    if (BF16OUT) {
        unsigned pk[4];
        #pragma unroll
        for (int d = 0; d < 4; ++d) {
            union { float f; unsigned u; } v0, v1;
            v0.f = o[2 * d]; v1.f = o[2 * d + 1];
            const unsigned r0 = (v0.u + 0x7FFFu + ((v0.u >> 16) & 1u)) >> 16;
            const unsigned r1 = (v1.u + 0x7FFFu + ((v1.u >> 16) & 1u)) >> 16;
            pk[d] = r0 | (r1 << 16);
        }
        uint4 v; v.x = pk[0]; v.y = pk[1]; v.z = pk[2]; v.w = pk[3];
        reinterpret_cast<uint4*>(outp)[(size_t)(b * NN + j) * 2 + h / 4];  // unused path
        (void)v;
    } else {
        float4* po = reinterpret_cast<float4*>(reinterpret_cast<float*>(outp) + (b * NN + j) * 64 + h * 8);
        po[0] = make_float4(o[0], o[1], o[2], o[3]);
        po[1] = make_float4(o[4], o[5], o[6], o[7]);
    }
}

} // namespace

extern "C" void kernel_launch(void* const* d_in, const int* in_sizes, int n_in,
                              void* d_out, int out_size, void* d_ws, size_t ws_size,
                              hipStream_t stream) {
    const float* n_in0  = (const float*)d_in[0];   // [B,N,64]
    const int*   adj    = (const int*)d_in[1];     // [B,N,N]
    const float* W1     = (const float*)d_in[2];
    const float* asrc1  = (const float*)d_in[3];
    const float* adst1  = (const float*)d_in[4];
    const float* b1     = (const float*)d_in[5];
    const float* W2     = (const float*)d_in[6];
    const float* asrc2  = (const float*)d_in[7];
    const float* adst2  = (const float*)d_in[8];
    const float* b2     = (const float*)d_in[9];

    float* ws = (float*)d_ws;
    float* xp   = ws;                 // 1048576 floats
    float* s    = xp + 1048576;       // 131072
    float* t    = s + 131072;         // 131072
    float* smax = t + 131072;         // 256
    float* x2   = smax + 256;         // 1048576

    const dim3 blk(256);
    const dim3 gProj(NB * NN / 32);
    const dim3 gSmax(NB);
    const dim3 gAggr(NN / 32, NB);

    // Layer 1
    gat_proj<<<gProj, blk, 0, stream>>>(n_in0, W1, asrc1, adst1, xp, s, t);
    gat_smax<<<gSmax, blk, 0, stream>>>(s, smax);
    gat_aggr<false><<<gAggr, blk, 0, stream>>>(xp, s, t, smax, adj, b1, (void*)x2);
    // Layer 2
    gat_proj<<<gProj, blk, 0, stream>>>(x2, W2, asrc2, adst2, xp, s, t);
    gat_smax<<<gSmax, blk, 0, stream>>>(s, smax);
    gat_aggr<false><<<gAggr, blk, 0, stream>>>(xp, s, t, smax, adj, b2, d_out);
}